// Round 6
// baseline (700.033 us; speedup 1.0000x reference)
//
#include <hip/hip_runtime.h>

#define DIN 64
#define DOUT 64
#define MAXK 32
#define KSPLIT 8
#define QG 128          // queries per coarse bucket (phaseB2 LDS accum = QG*64*4 = 32KB)

typedef __bf16 bf16x8 __attribute__((ext_vector_type(8)));
typedef float  f32x4  __attribute__((ext_vector_type(4)));
typedef unsigned int u32x4 __attribute__((ext_vector_type(4)));

static __device__ inline unsigned short f2b(float x) {
    return __builtin_bit_cast(unsigned short, (__bf16)x);
}
static __device__ inline float b2f(unsigned short u) {
    return __uint_as_float(((unsigned int)u) << 16);
}

// ---------------- fused conv_w + coarse hist ----------------
// Round 16: qcount pre-zeroed by hipMemsetAsync; hist blocks FIRST (dispatch
// order -> they start immediately), conv_w role after. Roles independent.

__global__ __launch_bounds__(256) void pre_kernel(
    const float* __restrict__ W, unsigned short* __restrict__ Wt, int total,
    const int* __restrict__ eq, int E, int* __restrict__ qcount, int HB)
{
    const int t = threadIdx.x;
    if ((int)blockIdx.x < HB) {
        // ---- coarse histogram: bucket = q >> 7 (Q=128) ----
        __shared__ int l[1024];
        #pragma unroll
        for (int s4 = 0; s4 < 4; ++s4) l[t + s4 * 256] = 0;
        __syncthreads();
        const int stride = HB * 256;
        for (int i = (int)blockIdx.x * 256 + t; i < E; i += stride)
            atomicAdd(&l[((unsigned)eq[i]) >> 7], 1);
        __syncthreads();
        #pragma unroll
        for (int s4 = 0; s4 < 4; ++s4) {
            int v = l[t + s4 * 256];
            if (v) atomicAdd(&qcount[t + s4 * 256], v);   // block-aggregated only
        }
    } else {
        // ---- W[k][d1][d2] fp32 -> frag-major bf16 Wt ----
        int i = ((int)blockIdx.x - HB) * 256 + t;
        if (i < total) {
            int j    = i & 7;
            int lane = (i >> 3) & 63;
            int h    = (i >> 9) & 1;
            int tt   = (i >> 10) & 3;
            int k    = i >> 12;
            int col  = lane & 15;
            int quad = lane >> 4;
            int d1 = h * 32 + quad * 8 + j;
            int d2 = tt * 16 + col;
            Wt[i] = f2b(W[(k * 64 + d1) * 64 + d2]);
        }
    }
}

// ---------------- coarse scan (single block) ----------------
__global__ void p1_scan_kernel(const int* __restrict__ qcount,
                               int* __restrict__ gbase, int* __restrict__ gcursor,
                               int NB) {
    __shared__ int sh[1024];
    int t = threadIdx.x;
    int v = (t < NB) ? qcount[t] : 0;
    sh[t] = v;
    __syncthreads();
    #pragma unroll
    for (int o = 1; o < 1024; o <<= 1) {
        int x = (t >= o) ? sh[t - o] : 0;
        __syncthreads();
        sh[t] += x;
        __syncthreads();
    }
    int ex = sh[t] - v;
    if (t < NB) { gbase[t] = ex; gcursor[t] = ex; }
}

// ---------------- Phase A body (round-5 proven: 70us @ 3.9 TB/s, BW-bound) ----------------
// T layout: [k][N][d2]; epilogue via LDS transpose -> coalesced 16B stores.
// Stores CACHED (not nt): nt caused 1.5x write amp (round 9).

static __device__ __forceinline__ void phaseA_body(
    const float* __restrict__ ref,
    const unsigned short* __restrict__ Wt,
    unsigned short* __restrict__ T,
    int K0, int Nn, int nblk, int k0, int k1, char* lds)
{
    const int lane = threadIdx.x & 63;
    const int wid  = threadIdx.x >> 6;
    const int col  = lane & 15;
    const int quad = lane >> 4;
    const int n0   = nblk * 64 + wid * 16;
    const int row  = n0 + col;
    char* bufs = lds + wid * 2 * 2304;

    const float* rp = ref + (size_t)row * 64;
    f32x4 r0 = *reinterpret_cast<const f32x4*>(rp + quad * 8);
    f32x4 r1 = *reinterpret_cast<const f32x4*>(rp + quad * 8 + 4);
    f32x4 r2 = *reinterpret_cast<const f32x4*>(rp + 32 + quad * 8);
    f32x4 r3 = *reinterpret_cast<const f32x4*>(rp + 32 + quad * 8 + 4);
    bf16x8 b0, b1;
    #pragma unroll
    for (int i = 0; i < 4; ++i) {
        b0[i]     = (__bf16)r0[i];
        b0[4 + i] = (__bf16)r1[i];
        b1[i]     = (__bf16)r2[i];
        b1[4 + i] = (__bf16)r3[i];
    }

    const int rrow = lane >> 2;
    const int rq   = lane & 3;

    for (int k = k0; k < k1; ++k) {
        char* buf = bufs + (k & 1) * 2304;
        const unsigned short* Wk = Wt + (size_t)k * 4096;
        #pragma unroll
        for (int t = 0; t < 4; ++t) {
            const unsigned short* ap = Wk + (size_t)t * 1024 + lane * 8;
            bf16x8 a0 = *reinterpret_cast<const bf16x8*>(ap);
            bf16x8 a1 = *reinterpret_cast<const bf16x8*>(ap + 512);
            f32x4 c = {0.f, 0.f, 0.f, 0.f};
            c = __builtin_amdgcn_mfma_f32_16x16x32_bf16(a0, b0, c, 0, 0, 0);
            c = __builtin_amdgcn_mfma_f32_16x16x32_bf16(a1, b1, c, 0, 0, 0);
            unsigned int lo = (unsigned int)f2b(c[0]) | ((unsigned int)f2b(c[1]) << 16);
            unsigned int hi = (unsigned int)f2b(c[2]) | ((unsigned int)f2b(c[3]) << 16);
            *reinterpret_cast<uint2*>(buf + col * 144 + t * 32 + quad * 8) =
                make_uint2(lo, hi);
        }
        u32x4 v0 = *reinterpret_cast<const u32x4*>(buf + rrow * 144 + rq * 32);
        u32x4 v1 = *reinterpret_cast<const u32x4*>(buf + rrow * 144 + rq * 32 + 16);
        size_t gbase = ((size_t)k * Nn + n0 + rrow) * 64 + rq * 16;
        *reinterpret_cast<u32x4*>(T + gbase)     = v0;
        *reinterpret_cast<u32x4*>(T + gbase + 8) = v1;
    }
}

// ---------------- fused coarse scatter + phaseA ----------------
// Round 16: these are the two independent long poles (scatter ~60us
// latency-bound, phaseA ~70us BW-bound). Scatter blocks FIRST in the grid so
// they dispatch immediately; A blocks fill remaining CUs. Payload 8B:
// {r | k<<16 | (q&127)<<21} (needs N<=65536, K0<=32, QG=128).
// All bucket atomics LDS-aggregated (per-edge global atomics FORBIDDEN, r13).

__global__ __launch_bounds__(256) void fusedA_scatter_kernel(
    const float* __restrict__ ref, const unsigned short* __restrict__ Wt,
    unsigned short* __restrict__ T, int K0, int Nn, int SCB, int NA,
    const int* __restrict__ eq, const int* __restrict__ er,
    const int* __restrict__ ek, const float* __restrict__ ew,
    int E, int* __restrict__ gcursor, uint2* __restrict__ tmp)
{
    __shared__ __align__(16) char ldsbuf[4 * 2 * 2304];
    __shared__ int bin[1024];
    __shared__ int base[1024];
    const int t = threadIdx.x;

    if ((int)blockIdx.x < SCB) {
        // ---- block-aggregated scatter into coarse buckets ----
        #pragma unroll
        for (int s4 = 0; s4 < 4; ++s4) bin[t + s4 * 256] = 0;
        __syncthreads();
        const int i0 = (int)blockIdx.x * 4096;
        unsigned key[16];
        unsigned rank[16];
        uint2 pay[16];
        #pragma unroll
        for (int u = 0; u < 16; ++u) {
            int i = i0 + u * 256 + t;
            if (i < E) {
                int q = eq[i];
                unsigned b = ((unsigned)q) >> 7;
                key[u] = b;
                rank[u] = atomicAdd(&bin[b], 1);
                pay[u] = make_uint2((unsigned)er[i] | ((unsigned)ek[i] << 16) |
                                    ((unsigned)(q & (QG - 1)) << 21),
                                    __float_as_uint(ew[i]));
            } else {
                key[u] = 0xFFFFFFFFu;
            }
        }
        __syncthreads();
        #pragma unroll
        for (int s4 = 0; s4 < 4; ++s4) {
            int bb = t + s4 * 256;
            int c = bin[bb];
            if (c) base[bb] = atomicAdd(&gcursor[bb], c);
        }
        __syncthreads();
        #pragma unroll
        for (int u = 0; u < 16; ++u) {
            if (key[u] != 0xFFFFFFFFu)
                tmp[(size_t)base[key[u]] + rank[u]] = pay[u];
        }
    } else {
        // ---- phaseA slice ----
        const int ab   = (int)blockIdx.x - SCB;
        const int nblk = ab % NA;
        const int ky   = ab / NA;
        const int kch  = (K0 + KSPLIT - 1) / KSPLIT;
        const int k0   = ky * kch;
        if (k0 >= K0) return;
        int k1 = k0 + kch;
        if (k1 > K0) k1 = K0;
        phaseA_body(ref, Wt, T, K0, Nn, nblk, k0, k1, ldsbuf);
    }
}

// ---------------- Phase B2: bucket-resident gather-accumulate ----------------
// Round 16: replaces p2 + per-query phaseB. One block per coarse bucket
// (QG=128 queries); reads the bucket's tmp segment sequentially, 8-deep
// random T-row gathers (proven pattern), accumulates into 32KB LDS
// acc[128][64] via LDS atomicAdd (ds_add_f32: lane-consecutive -> conflict-
// free; cross-wave same-q collisions rare). One coalesced out write.
// Do NOT use nontemporal/deeper buffering on the T gathers (round 10).

__global__ __launch_bounds__(512) void phaseB2_kernel(
    const unsigned short* __restrict__ T,    // [K0][N][64] bf16
    const uint2* __restrict__ tmp,
    const int* __restrict__ gbase, const int* __restrict__ qcount,
    float* __restrict__ out, int Nn)
{
    __shared__ float acc[QG * 64];
    const int t    = threadIdx.x;
    const int lane = t & 63;
    const int wid  = t >> 6;                 // 8 waves
    const int b    = blockIdx.x;

    #pragma unroll
    for (int i = 0; i < (QG * 64) / 512; ++i) acc[t + i * 512] = 0.f;
    __syncthreads();

    const int s   = gbase[b];
    const int L   = qcount[b];
    const int end = s + L;
    const int G   = L >> 3;                  // full 8-groups

    for (int g = wid; g < G; g += 8) {
        const int j0 = s + g * 8;
        float partial[8];
        int   qv[8];
        #pragma unroll
        for (int u = 0; u < 8; ++u) {
            uint2 v = tmp[j0 + u];
            unsigned mx = (unsigned)__builtin_amdgcn_readfirstlane((int)v.x);
            unsigned mw = (unsigned)__builtin_amdgcn_readfirstlane((int)v.y);
            unsigned off = (((mx >> 16) & 31) * (unsigned)Nn + (mx & 0xFFFFu)) * 64u
                           + (unsigned)lane;
            partial[u] = __uint_as_float(mw) * b2f(T[off]);
            qv[u] = (int)((mx >> 21) & (QG - 1));
        }
        #pragma unroll
        for (int u = 0; u < 8; ++u)
            atomicAdd(&acc[qv[u] * 64 + lane], partial[u]);
    }
    if (wid == 0) {                          // tail (<8 edges)
        for (int j = s + (G << 3); j < end; ++j) {
            uint2 v = tmp[j];
            unsigned mx = (unsigned)__builtin_amdgcn_readfirstlane((int)v.x);
            unsigned mw = (unsigned)__builtin_amdgcn_readfirstlane((int)v.y);
            unsigned off = (((mx >> 16) & 31) * (unsigned)Nn + (mx & 0xFFFFu)) * 64u
                           + (unsigned)lane;
            atomicAdd(&acc[(int)((mx >> 21) & (QG - 1)) * 64 + lane],
                      __uint_as_float(mw) * b2f(T[off]));
        }
    }
    __syncthreads();

    const size_t ob = (size_t)b * QG * 64;
    #pragma unroll
    for (int i = 0; i < (QG * 64) / 512; ++i)
        out[ob + t + i * 512] = acc[t + i * 512];
}

// ================= fallback path (round-1): kernel-bucketed fp32 =================

__global__ void hist_kernel(const int* __restrict__ ek, int E, int* __restrict__ counts) {
    __shared__ int l[MAXK];
    if (threadIdx.x < MAXK) l[threadIdx.x] = 0;
    __syncthreads();
    int stride = gridDim.x * blockDim.x;
    for (int i = blockIdx.x * blockDim.x + threadIdx.x; i < E; i += stride)
        atomicAdd(&l[ek[i]], 1);
    __syncthreads();
    if (threadIdx.x < MAXK) {
        int v = l[threadIdx.x];
        if (v) atomicAdd(&counts[threadIdx.x], v);
    }
}

__global__ void scan_kernel(const int* __restrict__ counts, int K,
                            int* __restrict__ start, int* __restrict__ cursor) {
    if (threadIdx.x == 0 && blockIdx.x == 0) {
        int acc = 0;
        for (int k = 0; k < K; ++k) {
            start[k] = acc;
            cursor[k] = acc;
            acc += counts[k];
        }
    }
}

__global__ void scatter_kernel(const int* __restrict__ ek, int E,
                               int* __restrict__ cursor, int* __restrict__ sorted) {
    __shared__ int lcnt[MAXK], lbase[MAXK], lpos[MAXK];
    if (threadIdx.x < MAXK) { lcnt[threadIdx.x] = 0; lpos[threadIdx.x] = 0; }
    __syncthreads();
    int i = blockIdx.x * blockDim.x + threadIdx.x;
    int k = 0;
    bool valid = (i < E);
    if (valid) { k = ek[i]; atomicAdd(&lcnt[k], 1); }
    __syncthreads();
    if (threadIdx.x < MAXK) {
        int v = lcnt[threadIdx.x];
        if (v) lbase[threadIdx.x] = atomicAdd(&cursor[threadIdx.x], v);
    }
    __syncthreads();
    if (valid) {
        int slot = lbase[k] + atomicAdd(&lpos[k], 1);
        sorted[slot] = i;
    }
}

__global__ __launch_bounds__(256) void mp_bucket_kernel(
    const float* __restrict__ W, const float* __restrict__ ref,
    const int* __restrict__ e_ref, const int* __restrict__ e_query,
    const float* __restrict__ e_weight, const int* __restrict__ sorted,
    const int* __restrict__ start, const int* __restrict__ counts,
    float* __restrict__ out)
{
    const int k = blockIdx.y;
    const int lane = threadIdx.x & 63;
    const int wid = threadIdx.x >> 6;

    float wreg[DIN];
    const float* Wk = W + k * DIN * DOUT;
    #pragma unroll
    for (int d = 0; d < DIN; ++d) wreg[d] = Wk[d * DOUT + lane];

    const int s = start[k];
    const int c = counts[k];
    const int nwaves = gridDim.x * 4;

    for (int i = blockIdx.x * 4 + wid; i < c; i += nwaves) {
        int eid = __builtin_amdgcn_readfirstlane(sorted[s + i]);
        int r = e_ref[eid];
        int q = e_query[eid];
        float w = e_weight[eid];
        const float* row = ref + r * DIN;
        float a0 = 0.f, a1 = 0.f, a2 = 0.f, a3 = 0.f;
        #pragma unroll
        for (int d = 0; d < DIN; d += 4) {
            a0 += row[d + 0] * wreg[d + 0];
            a1 += row[d + 1] * wreg[d + 1];
            a2 += row[d + 2] * wreg[d + 2];
            a3 += row[d + 3] * wreg[d + 3];
        }
        atomicAdd(&out[q * DOUT + lane], ((a0 + a1) + (a2 + a3)) * w);
    }
}

// =================================================================================

extern "C" void kernel_launch(void* const* d_in, const int* in_sizes, int n_in,
                              void* d_out, int out_size, void* d_ws, size_t ws_size,
                              hipStream_t stream) {
    const float* W        = (const float*)d_in[0];   // [K0, 64, 64]
    const float* ref      = (const float*)d_in[1];   // [N, 64]
    const int*   e_kernel = (const int*)d_in[2];     // [E]
    const int*   e_ref    = (const int*)d_in[3];     // [E]
    const int*   e_query  = (const int*)d_in[4];     // [E]
    const float* e_weight = (const float*)d_in[6];   // [E]

    const int K0 = in_sizes[0] / (DIN * DOUT);
    const int N  = in_sizes[1] / DIN;
    const int E  = in_sizes[2];
    const int M  = out_size / DOUT;
    const int KD = K0 * 64;
    const int NB = M / QG;           // coarse buckets (Q=128)

    float* out = (float*)d_out;

    // ---- plan A workspace carve ----
    size_t off = 0;
    auto alloc = [&](size_t bytes, size_t align) {
        off = (off + align - 1) / align * align;
        size_t r = off; off += bytes; return r;
    };
    size_t o_tmp     = alloc((size_t)E * 8, 16);
    size_t o_qcount  = alloc(1024 * 4, 4);
    size_t o_gbase   = alloc(1024 * 4, 4);
    size_t o_gcursor = alloc(1024 * 4, 4);
    size_t o_wt      = alloc((size_t)K0 * 4096 * 2, 16);
    size_t o_T       = alloc((size_t)N * KD * 2, 16);
    size_t needA = off;

    bool planA_ok = (ws_size >= needA) && (M % QG == 0) && (NB >= 1) && (NB <= 1024) &&
                    (N % 64 == 0) && (N <= 65536) && (K0 <= 32);

    if (planA_ok) {
        char* ws = (char*)d_ws;
        uint2* tmp           = (uint2*)(ws + o_tmp);
        int*  qcount         = (int*)(ws + o_qcount);
        int*  gbase          = (int*)(ws + o_gbase);
        int*  gcursor        = (int*)(ws + o_gcursor);
        unsigned short* Wt   = (unsigned short*)(ws + o_wt);
        unsigned short* T    = (unsigned short*)(ws + o_T);

        const int HB   = 512;                       // hist blocks
        const int CWB  = (K0 * 4096 + 255) / 256;   // conv_w blocks
        const int SCB  = (E + 4095) / 4096;         // scatter blocks
        const int NA   = N / 64;                    // phaseA n-blocks

        hipMemsetAsync(qcount, 0, 1024 * sizeof(int), stream);

        pre_kernel<<<HB + CWB, 256, 0, stream>>>(W, Wt, K0 * 4096,
                                                 e_query, E, qcount, HB);

        p1_scan_kernel<<<1, 1024, 0, stream>>>(qcount, gbase, gcursor, NB);

        fusedA_scatter_kernel<<<SCB + NA * KSPLIT, 256, 0, stream>>>(
            ref, Wt, T, K0, N, SCB, NA,
            e_query, e_ref, e_kernel, e_weight, E, gcursor, tmp);

        phaseB2_kernel<<<NB, 512, 0, stream>>>(T, tmp, gbase, qcount, out, N);
    } else {
        hipMemsetAsync(out, 0, (size_t)out_size * sizeof(float), stream);
        size_t needB = (size_t)(96 + E) * sizeof(int);
        if (ws_size >= needB) {
            int* ws_i   = (int*)d_ws;
            int* counts = ws_i;
            int* start  = ws_i + 32;
            int* cursor = ws_i + 64;
            int* sorted = ws_i + 96;
            hipMemsetAsync(counts, 0, 96 * sizeof(int), stream);
            hist_kernel<<<512, 256, 0, stream>>>(e_kernel, E, counts);
            scan_kernel<<<1, 64, 0, stream>>>(counts, K0, start, cursor);
            scatter_kernel<<<(E + 255) / 256, 256, 0, stream>>>(e_kernel, E, cursor, sorted);
            dim3 grid(64, K0);
            mp_bucket_kernel<<<grid, 256, 0, stream>>>(W, ref, e_ref, e_query, e_weight,
                                                       sorted, start, counts, out);
        }
    }
}

// Round 7
// 274.880 us; speedup vs baseline: 2.5467x; 2.5467x over previous
//
#include <hip/hip_runtime.h>

#define DIN 64
#define DOUT 64
#define MAXK 32
#define KSPLIT 8
#define KS4 5            // k-slices fused with scatter stage (rest ride p2 stage)
#define QG 128           // queries per coarse bucket -> NB = M/128 buckets

typedef __bf16 bf16x8 __attribute__((ext_vector_type(8)));
typedef float  f32x4  __attribute__((ext_vector_type(4)));
typedef unsigned int u32x4 __attribute__((ext_vector_type(4)));

static __device__ inline unsigned short f2b(float x) {
    return __builtin_bit_cast(unsigned short, (__bf16)x);
}
static __device__ inline float b2f(unsigned short u) {
    return __uint_as_float(((unsigned int)u) << 16);
}

// ---------------- fused conv_w + coarse hist (proven round-6 piece) ----------------
__global__ __launch_bounds__(256) void pre_kernel(
    const float* __restrict__ W, unsigned short* __restrict__ Wt, int total,
    const int* __restrict__ eq, int E, int* __restrict__ qcount, int HB)
{
    const int t = threadIdx.x;
    if ((int)blockIdx.x < HB) {
        __shared__ int l[512];
        l[t] = 0; l[t + 256] = 0;
        __syncthreads();
        const int stride = HB * 256;
        for (int i = (int)blockIdx.x * 256 + t; i < E; i += stride)
            atomicAdd(&l[((unsigned)eq[i]) >> 7], 1);
        __syncthreads();
        int v0 = l[t];       if (v0) atomicAdd(&qcount[t], v0);
        int v1 = l[t + 256]; if (v1) atomicAdd(&qcount[t + 256], v1);
    } else {
        int i = ((int)blockIdx.x - HB) * 256 + t;
        if (i < total) {
            int j    = i & 7;
            int lane = (i >> 3) & 63;
            int h    = (i >> 9) & 1;
            int tt   = (i >> 10) & 3;
            int k    = i >> 12;
            int col  = lane & 15;
            int quad = lane >> 4;
            int d1 = h * 32 + quad * 8 + j;
            int d2 = tt * 16 + col;
            Wt[i] = f2b(W[(k * 64 + d1) * 64 + d2]);
        }
    }
}

// ---------------- coarse scan (single block, 1024 thr) ----------------
__global__ void p1_scan_kernel(const int* __restrict__ qcount,
                               int* __restrict__ gbase, int* __restrict__ gcursor,
                               int* __restrict__ qstart, int NB, int M, int E) {
    __shared__ int sh[1024];
    int t = threadIdx.x;
    int v = (t < NB) ? qcount[t] : 0;
    sh[t] = v;
    __syncthreads();
    #pragma unroll
    for (int o = 1; o < 1024; o <<= 1) {
        int x = (t >= o) ? sh[t - o] : 0;
        __syncthreads();
        sh[t] += x;
        __syncthreads();
    }
    int ex = sh[t] - v;
    if (t < NB) { gbase[t] = ex; gcursor[t] = ex; }
    if (t == 0) qstart[M] = E;
}

// ---------------- Phase A body, 16-wave (1024-thr) blocks ----------------
// Single LDS buffer per wave (round-0 proven: wave-private region, lgkmcnt
// ordering; ping-pong measured neutral r12). T layout [k][N][d2]; CACHED
// stores (nt = 1.5x write amp, r9). BW-floor ~70us full-machine (r5 counter).

static __device__ __forceinline__ void phaseA_body16(
    const float* __restrict__ ref,
    const unsigned short* __restrict__ Wt,
    unsigned short* __restrict__ T,
    int K0, int Nn, int nblk, int k0, int k1, char* lds)
{
    const int t    = threadIdx.x;
    const int lane = t & 63;
    const int wid  = t >> 6;                 // 16 waves
    const int col  = lane & 15;
    const int quad = lane >> 4;
    const int n0   = nblk * 256 + wid * 16;
    const int row  = n0 + col;
    char* buf = lds + wid * 2304;

    const float* rp = ref + (size_t)row * 64;
    f32x4 r0 = *reinterpret_cast<const f32x4*>(rp + quad * 8);
    f32x4 r1 = *reinterpret_cast<const f32x4*>(rp + quad * 8 + 4);
    f32x4 r2 = *reinterpret_cast<const f32x4*>(rp + 32 + quad * 8);
    f32x4 r3 = *reinterpret_cast<const f32x4*>(rp + 32 + quad * 8 + 4);
    bf16x8 b0, b1;
    #pragma unroll
    for (int i = 0; i < 4; ++i) {
        b0[i]     = (__bf16)r0[i];
        b0[4 + i] = (__bf16)r1[i];
        b1[i]     = (__bf16)r2[i];
        b1[4 + i] = (__bf16)r3[i];
    }

    const int rrow = lane >> 2;
    const int rq   = lane & 3;

    for (int k = k0; k < k1; ++k) {
        const unsigned short* Wk = Wt + (size_t)k * 4096;
        #pragma unroll
        for (int tt = 0; tt < 4; ++tt) {
            const unsigned short* ap = Wk + (size_t)tt * 1024 + lane * 8;
            bf16x8 a0 = *reinterpret_cast<const bf16x8*>(ap);
            bf16x8 a1 = *reinterpret_cast<const bf16x8*>(ap + 512);
            f32x4 c = {0.f, 0.f, 0.f, 0.f};
            c = __builtin_amdgcn_mfma_f32_16x16x32_bf16(a0, b0, c, 0, 0, 0);
            c = __builtin_amdgcn_mfma_f32_16x16x32_bf16(a1, b1, c, 0, 0, 0);
            unsigned int lo = (unsigned int)f2b(c[0]) | ((unsigned int)f2b(c[1]) << 16);
            unsigned int hi = (unsigned int)f2b(c[2]) | ((unsigned int)f2b(c[3]) << 16);
            *reinterpret_cast<uint2*>(buf + col * 144 + tt * 32 + quad * 8) =
                make_uint2(lo, hi);
        }
        u32x4 v0 = *reinterpret_cast<const u32x4*>(buf + rrow * 144 + rq * 32);
        u32x4 v1 = *reinterpret_cast<const u32x4*>(buf + rrow * 144 + rq * 32 + 16);
        size_t gb = ((size_t)k * Nn + n0 + rrow) * 64 + rq * 16;
        *reinterpret_cast<u32x4*>(T + gb)     = v0;
        *reinterpret_cast<u32x4*>(T + gb + 8) = v1;
    }
}

// ---------------- fused coarse scatter + phaseA (k-slices 0..KS4) ----------------
// Round 17: sort stages rebuilt for TLP -- 1024-thr blocks, shallow per-thread
// chains (8-deep). Payload 8B: {r | k<<16 | (q&127)<<21} (N<=65536, K0<=32).
// All bucket atomics LDS-aggregated (per-edge global atomics FORBIDDEN, r13).

__global__ __launch_bounds__(1024) void fusedA_scatter_kernel(
    const float* __restrict__ ref, const unsigned short* __restrict__ Wt,
    unsigned short* __restrict__ T, int K0, int Nn, int SCB, int NA2,
    const int* __restrict__ eq, const int* __restrict__ er,
    const int* __restrict__ ek, const float* __restrict__ ew,
    int E, int* __restrict__ gcursor, uint2* __restrict__ tmp)
{
    __shared__ __align__(16) char ldsbuf[16 * 2304];
    __shared__ int bin[512];
    __shared__ int base[512];
    const int t = threadIdx.x;

    if ((int)blockIdx.x < SCB) {
        if (t < 512) bin[t] = 0;
        __syncthreads();
        const int i0 = (int)blockIdx.x * 8192;
        unsigned key[8];
        unsigned rank[8];
        uint2 pay[8];
        #pragma unroll
        for (int u = 0; u < 8; ++u) {
            int i = i0 + u * 1024 + t;
            if (i < E) {
                int q = eq[i];
                unsigned b = ((unsigned)q) >> 7;
                key[u] = b;
                rank[u] = atomicAdd(&bin[b], 1);
                pay[u] = make_uint2((unsigned)er[i] | ((unsigned)ek[i] << 16) |
                                    ((unsigned)(q & (QG - 1)) << 21),
                                    __float_as_uint(ew[i]));
            } else {
                key[u] = 0xFFFFFFFFu;
            }
        }
        __syncthreads();
        if (t < 512) {
            int c = bin[t];
            if (c) base[t] = atomicAdd(&gcursor[t], c);
        }
        __syncthreads();
        #pragma unroll
        for (int u = 0; u < 8; ++u) {
            if (key[u] != 0xFFFFFFFFu)
                tmp[(size_t)base[key[u]] + rank[u]] = pay[u];
        }
    } else {
        const int ab   = (int)blockIdx.x - SCB;
        const int nblk = ab % NA2;
        const int ky   = ab / NA2;           // 0..KS4-1
        const int kch  = (K0 + KSPLIT - 1) / KSPLIT;
        const int k0   = ky * kch;
        if (k0 >= K0) return;
        int k1 = k0 + kch;
        if (k1 > K0) k1 = K0;
        phaseA_body16(ref, Wt, T, K0, Nn, nblk, k0, k1, ldsbuf);
    }
}

// ---------------- fused fine sort (p2) + phaseA (k-slices KS4..KSPLIT) ----------------
// p2: 1024-thr blocks, L~3072 -> 3 serial iterations/pass (was 24 at NB=256).
__global__ __launch_bounds__(1024) void fusedA_p2_kernel(
    const float* __restrict__ ref, const unsigned short* __restrict__ Wt,
    unsigned short* __restrict__ T, int K0, int Nn, int NB, int NA2,
    const uint2* __restrict__ tmp, const int* __restrict__ gbase,
    const int* __restrict__ qcount, uint2* __restrict__ rec,
    int* __restrict__ qstart)
{
    __shared__ __align__(16) char ldsbuf[16 * 2304];
    __shared__ int fine[QG];
    __shared__ int foff[QG];
    __shared__ int vsave[QG];
    const int t = threadIdx.x;

    if ((int)blockIdx.x < NB) {
        const int b = (int)blockIdx.x;
        const int s = gbase[b];
        const int L = qcount[b];
        if (t < QG) fine[t] = 0;
        __syncthreads();
        for (int i = t; i < L; i += 1024)
            atomicAdd(&fine[(tmp[s + i].x >> 21) & (QG - 1)], 1);
        __syncthreads();
        if (t < QG) vsave[t] = fine[t];
        __syncthreads();
        #pragma unroll
        for (int o = 1; o < QG; o <<= 1) {
            int x = (t >= o && t < QG) ? fine[t - o] : 0;
            __syncthreads();
            if (t < QG) fine[t] += x;
            __syncthreads();
        }
        if (t < QG) {
            int ex = fine[t] - vsave[t];
            foff[t] = ex;
            qstart[b * QG + t] = s + ex;
            fine[t] = 0;
        }
        __syncthreads();
        for (int i = t; i < L; i += 1024) {
            uint2 p = tmp[s + i];
            unsigned fb = (p.x >> 21) & (QG - 1);
            int r = atomicAdd(&fine[fb], 1);
            rec[(size_t)s + foff[fb] + r] = p;
        }
    } else {
        const int ab   = (int)blockIdx.x - NB;
        const int nblk = ab % NA2;
        const int ky   = KS4 + ab / NA2;     // KS4..KSPLIT-1
        const int kch  = (K0 + KSPLIT - 1) / KSPLIT;
        const int k0   = ky * kch;
        if (k0 >= K0) return;
        int k1 = k0 + kch;
        if (k1 > K0) k1 = K0;
        phaseA_body16(ref, Wt, T, K0, Nn, nblk, k0, k1, ldsbuf);
    }
}

// ---------------- Phase B: per-query gather-accumulate (PROVEN; do not shrink grid) ----------------
// 65us @ 3.4 TB/s, 201MB compulsory fetch. Lives on massive TLP (65K waves):
// round-6 bucket-resident variant (4K waves) was 517us. No nontemporal loads,
// no deeper buffering (round 10).

__global__ __launch_bounds__(256) void phaseB_kernel(
    const unsigned short* __restrict__ T,    // [K0][N][64] bf16
    const uint2* __restrict__ rec,
    const int* __restrict__ qstart,
    float* __restrict__ out, int Nn)
{
    const int lane = threadIdx.x & 63;
    const int wid  = threadIdx.x >> 6;
    const int q    = blockIdx.x * 4 + wid;

    int beg = qstart[q];
    int end = qstart[q + 1];
    int cnt = end - beg;
    float acc = 0.f;

    if (cnt <= 64) {
        uint2 rv = make_uint2(0u, 0u);
        if (lane < cnt) rv = rec[beg + lane];
        int j = 0;
        for (; j + 8 <= cnt; j += 8) {
            float partial[8];
            #pragma unroll
            for (int u = 0; u < 8; ++u) {
                unsigned mx = (unsigned)__builtin_amdgcn_readlane((int)rv.x, j + u);
                unsigned mw = (unsigned)__builtin_amdgcn_readlane((int)rv.y, j + u);
                unsigned off = (((mx >> 16) & 31) * (unsigned)Nn + (mx & 0xFFFFu)) * 64u
                               + (unsigned)lane;
                partial[u] = __uint_as_float(mw) * b2f(T[off]);
            }
            #pragma unroll
            for (int u = 0; u < 8; ++u) acc += partial[u];
        }
        for (; j < cnt; ++j) {
            unsigned mx = (unsigned)__builtin_amdgcn_readlane((int)rv.x, j);
            unsigned mw = (unsigned)__builtin_amdgcn_readlane((int)rv.y, j);
            unsigned off = (((mx >> 16) & 31) * (unsigned)Nn + (mx & 0xFFFFu)) * 64u
                           + (unsigned)lane;
            acc = fmaf(__uint_as_float(mw), b2f(T[off]), acc);
        }
    } else {
        for (int j = beg; j < end; ++j) {
            uint2 v0 = rec[j];
            unsigned m0 = __builtin_amdgcn_readfirstlane(v0.x);
            float w0 = __uint_as_float(__builtin_amdgcn_readfirstlane(v0.y));
            unsigned off = (((m0 >> 16) & 31) * (unsigned)Nn + (m0 & 0xFFFFu)) * 64u
                           + (unsigned)lane;
            acc = fmaf(w0, b2f(T[off]), acc);
        }
    }
    out[(size_t)q * 64 + lane] = acc;
}

// ================= fallback path (round-1): kernel-bucketed fp32 =================

__global__ void hist_kernel(const int* __restrict__ ek, int E, int* __restrict__ counts) {
    __shared__ int l[MAXK];
    if (threadIdx.x < MAXK) l[threadIdx.x] = 0;
    __syncthreads();
    int stride = gridDim.x * blockDim.x;
    for (int i = blockIdx.x * blockDim.x + threadIdx.x; i < E; i += stride)
        atomicAdd(&l[ek[i]], 1);
    __syncthreads();
    if (threadIdx.x < MAXK) {
        int v = l[threadIdx.x];
        if (v) atomicAdd(&counts[threadIdx.x], v);
    }
}

__global__ void scan_kernel(const int* __restrict__ counts, int K,
                            int* __restrict__ start, int* __restrict__ cursor) {
    if (threadIdx.x == 0 && blockIdx.x == 0) {
        int acc = 0;
        for (int k = 0; k < K; ++k) {
            start[k] = acc;
            cursor[k] = acc;
            acc += counts[k];
        }
    }
}

__global__ void scatter_kernel(const int* __restrict__ ek, int E,
                               int* __restrict__ cursor, int* __restrict__ sorted) {
    __shared__ int lcnt[MAXK], lbase[MAXK], lpos[MAXK];
    if (threadIdx.x < MAXK) { lcnt[threadIdx.x] = 0; lpos[threadIdx.x] = 0; }
    __syncthreads();
    int i = blockIdx.x * blockDim.x + threadIdx.x;
    int k = 0;
    bool valid = (i < E);
    if (valid) { k = ek[i]; atomicAdd(&lcnt[k], 1); }
    __syncthreads();
    if (threadIdx.x < MAXK) {
        int v = lcnt[threadIdx.x];
        if (v) lbase[threadIdx.x] = atomicAdd(&cursor[threadIdx.x], v);
    }
    __syncthreads();
    if (valid) {
        int slot = lbase[k] + atomicAdd(&lpos[k], 1);
        sorted[slot] = i;
    }
}

__global__ __launch_bounds__(256) void mp_bucket_kernel(
    const float* __restrict__ W, const float* __restrict__ ref,
    const int* __restrict__ e_ref, const int* __restrict__ e_query,
    const float* __restrict__ e_weight, const int* __restrict__ sorted,
    const int* __restrict__ start, const int* __restrict__ counts,
    float* __restrict__ out)
{
    const int k = blockIdx.y;
    const int lane = threadIdx.x & 63;
    const int wid = threadIdx.x >> 6;

    float wreg[DIN];
    const float* Wk = W + k * DIN * DOUT;
    #pragma unroll
    for (int d = 0; d < DIN; ++d) wreg[d] = Wk[d * DOUT + lane];

    const int s = start[k];
    const int c = counts[k];
    const int nwaves = gridDim.x * 4;

    for (int i = blockIdx.x * 4 + wid; i < c; i += nwaves) {
        int eid = __builtin_amdgcn_readfirstlane(sorted[s + i]);
        int r = e_ref[eid];
        int q = e_query[eid];
        float w = e_weight[eid];
        const float* row = ref + r * DIN;
        float a0 = 0.f, a1 = 0.f, a2 = 0.f, a3 = 0.f;
        #pragma unroll
        for (int d = 0; d < DIN; d += 4) {
            a0 += row[d + 0] * wreg[d + 0];
            a1 += row[d + 1] * wreg[d + 1];
            a2 += row[d + 2] * wreg[d + 2];
            a3 += row[d + 3] * wreg[d + 3];
        }
        atomicAdd(&out[q * DOUT + lane], ((a0 + a1) + (a2 + a3)) * w);
    }
}

// =================================================================================

extern "C" void kernel_launch(void* const* d_in, const int* in_sizes, int n_in,
                              void* d_out, int out_size, void* d_ws, size_t ws_size,
                              hipStream_t stream) {
    const float* W        = (const float*)d_in[0];   // [K0, 64, 64]
    const float* ref      = (const float*)d_in[1];   // [N, 64]
    const int*   e_kernel = (const int*)d_in[2];     // [E]
    const int*   e_ref    = (const int*)d_in[3];     // [E]
    const int*   e_query  = (const int*)d_in[4];     // [E]
    const float* e_weight = (const float*)d_in[6];   // [E]

    const int K0 = in_sizes[0] / (DIN * DOUT);
    const int N  = in_sizes[1] / DIN;
    const int E  = in_sizes[2];
    const int M  = out_size / DOUT;
    const int KD = K0 * 64;
    const int NB = M / QG;           // coarse buckets (Q=128)

    float* out = (float*)d_out;

    // ---- plan A workspace carve ----
    size_t off = 0;
    auto alloc = [&](size_t bytes, size_t align) {
        off = (off + align - 1) / align * align;
        size_t r = off; off += bytes; return r;
    };
    size_t o_tmp     = alloc((size_t)E * 8, 16);
    size_t o_rec     = alloc((size_t)E * 8, 16);
    size_t o_qstart  = alloc((size_t)(M + 1) * 4, 4);
    size_t o_qcount  = alloc(1024 * 4, 4);
    size_t o_gbase   = alloc(1024 * 4, 4);
    size_t o_gcursor = alloc(1024 * 4, 4);
    size_t o_wt      = alloc((size_t)K0 * 4096 * 2, 16);
    size_t o_T       = alloc((size_t)N * KD * 2, 16);
    size_t needA = off;

    bool planA_ok = (ws_size >= needA) && (M % QG == 0) && (NB >= 1) && (NB <= 512) &&
                    (N % 256 == 0) && (N <= 65536) && (K0 <= 32);

    if (planA_ok) {
        char* ws = (char*)d_ws;
        uint2* tmp           = (uint2*)(ws + o_tmp);
        uint2* rec           = (uint2*)(ws + o_rec);
        int*  qstart         = (int*)(ws + o_qstart);
        int*  qcount         = (int*)(ws + o_qcount);
        int*  gbase          = (int*)(ws + o_gbase);
        int*  gcursor        = (int*)(ws + o_gcursor);
        unsigned short* Wt   = (unsigned short*)(ws + o_wt);
        unsigned short* T    = (unsigned short*)(ws + o_T);

        const int HB   = 512;                       // hist blocks
        const int CWB  = (K0 * 4096 + 255) / 256;   // conv_w blocks
        const int SCB  = (E + 8191) / 8192;         // scatter blocks (1024 thr, 8-deep)
        const int NA2  = N / 256;                   // phaseA 16-wave n-blocks

        hipMemsetAsync(qcount, 0, 1024 * sizeof(int), stream);

        pre_kernel<<<HB + CWB, 256, 0, stream>>>(W, Wt, K0 * 4096,
                                                 e_query, E, qcount, HB);

        p1_scan_kernel<<<1, 1024, 0, stream>>>(qcount, gbase, gcursor, qstart, NB, M, E);

        fusedA_scatter_kernel<<<SCB + NA2 * KS4, 1024, 0, stream>>>(
            ref, Wt, T, K0, N, SCB, NA2,
            e_query, e_ref, e_kernel, e_weight, E, gcursor, tmp);

        fusedA_p2_kernel<<<NB + NA2 * (KSPLIT - KS4), 1024, 0, stream>>>(
            ref, Wt, T, K0, N, NB, NA2,
            tmp, gbase, qcount, rec, qstart);

        phaseB_kernel<<<M / 4, 256, 0, stream>>>(T, rec, qstart, out, N);
    } else {
        hipMemsetAsync(out, 0, (size_t)out_size * sizeof(float), stream);
        size_t needB = (size_t)(96 + E) * sizeof(int);
        if (ws_size >= needB) {
            int* ws_i   = (int*)d_ws;
            int* counts = ws_i;
            int* start  = ws_i + 32;
            int* cursor = ws_i + 64;
            int* sorted = ws_i + 96;
            hipMemsetAsync(counts, 0, 96 * sizeof(int), stream);
            hist_kernel<<<512, 256, 0, stream>>>(e_kernel, E, counts);
            scan_kernel<<<1, 64, 0, stream>>>(counts, K0, start, cursor);
            scatter_kernel<<<(E + 255) / 256, 256, 0, stream>>>(e_kernel, E, cursor, sorted);
            dim3 grid(64, K0);
            mp_bucket_kernel<<<grid, 256, 0, stream>>>(W, ref, e_ref, e_query, e_weight,
                                                       sorted, start, counts, out);
        }
    }
}